// Round 2
// baseline (245.796 us; speedup 1.0000x reference)
//
#include <hip/hip_runtime.h>
#include <hip/hip_bf16.h>

#define NB   1024
#define SINQ 256
#define SPRQ 128
#define HIDQ 512

// Block-wide mean / rstd over (nthr threads * 3 values each) = nelem.
__device__ __forceinline__ void block_stats(float s1, float s2, float* sRed,
                                            int tid, int nthr, float nelem,
                                            float& mean, float& rstd) {
#pragma unroll
  for (int off = 32; off > 0; off >>= 1) {
    s1 += __shfl_xor(s1, off, 64);
    s2 += __shfl_xor(s2, off, 64);
  }
  __syncthreads();  // protect sRed reuse across calls
  if ((tid & 63) == 0) {
    sRed[((tid >> 6) << 1) + 0] = s1;
    sRed[((tid >> 6) << 1) + 1] = s2;
  }
  __syncthreads();
  float t1 = 0.f, t2 = 0.f;
  const int nw = nthr >> 6;
  for (int w = 0; w < nw; ++w) { t1 += sRed[2 * w]; t2 += sRed[2 * w + 1]; }
  mean = t1 / nelem;
  float var = t2 / nelem - mean * mean;
  rstd = rsqrtf(var + 1e-5f);
}

// pos_enc: emb[:, :3] = sin(pos * inv_freq[c]), c = 0,1,2
// inv_freq[c] = 10000^(-2c/256)
#define PEF1 0.93057207f
#define PEF2 0.86596438f
#define ISQ3 0.57735026919f

__global__ __launch_bounds__(256) void enc_fwd(
    const float* __restrict__ X,
    const float* __restrict__ inw, const float* __restrict__ inb,
    const float* __restrict__ ow,  const float* __restrict__ ob,
    const float* __restrict__ ln1w, const float* __restrict__ ln1b,
    const float* __restrict__ w1,  const float* __restrict__ b1,
    const float* __restrict__ w2,  const float* __restrict__ b2,
    const float* __restrict__ ln2w, const float* __restrict__ ln2b,
    float* __restrict__ enc_out)
{
  __shared__ float4 sK[SINQ];
  __shared__ float4 sV[SINQ];
  __shared__ float4 sW1[HIDQ];  // (w1_0, w1_1, w1_2, b1)
  __shared__ float4 sW2[HIDQ];  // (w2[0][k], w2[1][k], w2[2][k], 0)
  __shared__ float sRed[8];

  const int b = blockIdx.x;
  const int i = threadIdx.x;

  for (int k = i; k < HIDQ; k += 256) {
    sW1[k] = make_float4(w1[3 * k], w1[3 * k + 1], w1[3 * k + 2], b1[k]);
    sW2[k] = make_float4(w2[k], w2[HIDQ + k], w2[2 * HIDQ + k], 0.f);
  }

  // p_X row i
  const float pos = (float)i;
  const float* xr = X + ((size_t)b * SINQ + i) * 3;
  const float p0 = xr[0] + sinf(pos);
  const float p1 = xr[1] + sinf(pos * PEF1);
  const float p2 = xr[2] + sinf(pos * PEF2);

  // qkv (in_w rows: 0-2 = Wq, 3-5 = Wk, 6-8 = Wv; row-major (9,3))
  const float q0 = inw[0] * p0 + inw[1] * p1 + inw[2] * p2 + inb[0];
  const float q1 = inw[3] * p0 + inw[4] * p1 + inw[5] * p2 + inb[1];
  const float q2 = inw[6] * p0 + inw[7] * p1 + inw[8] * p2 + inb[2];
  const float k0 = inw[9]  * p0 + inw[10] * p1 + inw[11] * p2 + inb[3];
  const float k1 = inw[12] * p0 + inw[13] * p1 + inw[14] * p2 + inb[4];
  const float k2 = inw[15] * p0 + inw[16] * p1 + inw[17] * p2 + inb[5];
  const float v0 = inw[18] * p0 + inw[19] * p1 + inw[20] * p2 + inb[6];
  const float v1 = inw[21] * p0 + inw[22] * p1 + inw[23] * p2 + inb[7];
  const float v2 = inw[24] * p0 + inw[25] * p1 + inw[26] * p2 + inb[8];
  sK[i] = make_float4(k0, k1, k2, 0.f);
  sV[i] = make_float4(v0, v1, v2, 0.f);
  __syncthreads();

  // softmax(QK^T/sqrt(3)) @ V, fused (scores are O(1) -> direct exp is safe)
  float den = 0.f, o0 = 0.f, o1 = 0.f, o2 = 0.f;
  for (int j = 0; j < SINQ; ++j) {
    const float4 kk = sK[j];
    const float4 vv = sV[j];
    const float e = __expf((q0 * kk.x + q1 * kk.y + q2 * kk.z) * ISQ3);
    den += e;
    o0 = fmaf(e, vv.x, o0); o1 = fmaf(e, vv.y, o1); o2 = fmaf(e, vv.z, o2);
  }
  const float rd = 1.f / den;
  o0 *= rd; o1 *= rd; o2 *= rd;

  // out proj + residual
  float r0 = ow[0] * o0 + ow[1] * o1 + ow[2] * o2 + ob[0] + p0;
  float r1 = ow[3] * o0 + ow[4] * o1 + ow[5] * o2 + ob[1] + p1;
  float r2 = ow[6] * o0 + ow[7] * o1 + ow[8] * o2 + ob[2] + p2;

  // LN over all 768 elements of this batch slice (axes (-2,-1) jointly)
  float mean, rstd;
  block_stats(r0 + r1 + r2, r0 * r0 + r1 * r1 + r2 * r2, sRed, i, 256, 768.f, mean, rstd);
  const int li = i * 3;
  const float x20 = (r0 - mean) * rstd * ln1w[li + 0] + ln1b[li + 0];
  const float x21 = (r1 - mean) * rstd * ln1w[li + 1] + ln1b[li + 1];
  const float x22 = (r2 - mean) * rstd * ln1w[li + 2] + ln1b[li + 2];

  // FFN 3 -> 512 -> 3
  float c0 = 0.f, c1 = 0.f, c2 = 0.f;
  for (int k = 0; k < HIDQ; ++k) {
    const float4 wr = sW1[k];
    float h = fmaf(wr.x, x20, fmaf(wr.y, x21, fmaf(wr.z, x22, wr.w)));
    h = fmaxf(h, 0.f);
    const float4 wc = sW2[k];
    c0 = fmaf(h, wc.x, c0); c1 = fmaf(h, wc.y, c1); c2 = fmaf(h, wc.z, c2);
  }
  const float h0 = c0 + b2[0] + x20;
  const float h1 = c1 + b2[1] + x21;
  const float h2 = c2 + b2[2] + x22;

  block_stats(h0 + h1 + h2, h0 * h0 + h1 * h1 + h2 * h2, sRed, i, 256, 768.f, mean, rstd);
  float* eo = enc_out + ((size_t)b * SINQ + i) * 3;
  eo[0] = (h0 - mean) * rstd * ln2w[li + 0] + ln2b[li + 0];
  eo[1] = (h1 - mean) * rstd * ln2w[li + 1] + ln2b[li + 1];
  eo[2] = (h2 - mean) * rstd * ln2w[li + 2] + ln2b[li + 2];
}

__global__ __launch_bounds__(128) void dec_fwd(
    const float* __restrict__ T,
    const float* __restrict__ enc_out,
    const float* __restrict__ a1w, const float* __restrict__ a1b,
    const float* __restrict__ a1ow, const float* __restrict__ a1ob,
    const float* __restrict__ ln1w, const float* __restrict__ ln1b,
    const float* __restrict__ a2w, const float* __restrict__ a2b,
    const float* __restrict__ a2ow, const float* __restrict__ a2ob,
    const float* __restrict__ w1,  const float* __restrict__ b1,
    const float* __restrict__ w2,  const float* __restrict__ b2,
    const float* __restrict__ ln3w, const float* __restrict__ ln3b,
    float* __restrict__ out)
{
  __shared__ float4 sKs[SPRQ];
  __shared__ float4 sVs[SPRQ];
  __shared__ float4 sKc[SINQ];
  __shared__ float4 sVc[SINQ];
  __shared__ float4 sW1[HIDQ];
  __shared__ float4 sW2[HIDQ];
  __shared__ float sRed[4];

  const int b = blockIdx.x;
  const int i = threadIdx.x;

  for (int k = i; k < HIDQ; k += 128) {
    sW1[k] = make_float4(w1[3 * k], w1[3 * k + 1], w1[3 * k + 2], b1[k]);
    sW2[k] = make_float4(w2[k], w2[HIDQ + k], w2[2 * HIDQ + k], 0.f);
  }

  // cross-attn K,V from enc_out (a2w rows 3-5 = Wk, 6-8 = Wv)
  {
    float cw[18], cb[6];
#pragma unroll
    for (int t = 0; t < 18; ++t) cw[t] = a2w[9 + t];
#pragma unroll
    for (int t = 0; t < 6; ++t) cb[t] = a2b[3 + t];
    for (int r = i; r < SINQ; r += 128) {
      const float* e = enc_out + ((size_t)b * SINQ + r) * 3;
      const float e0 = e[0], e1 = e[1], e2 = e[2];
      sKc[r] = make_float4(cw[0] * e0 + cw[1] * e1 + cw[2] * e2 + cb[0],
                           cw[3] * e0 + cw[4] * e1 + cw[5] * e2 + cb[1],
                           cw[6] * e0 + cw[7] * e1 + cw[8] * e2 + cb[2], 0.f);
      sVc[r] = make_float4(cw[9]  * e0 + cw[10] * e1 + cw[11] * e2 + cb[3],
                           cw[12] * e0 + cw[13] * e1 + cw[14] * e2 + cb[4],
                           cw[15] * e0 + cw[16] * e1 + cw[17] * e2 + cb[5], 0.f);
    }
  }

  // p_T row i
  const float pos = (float)i;
  const float* tr = T + ((size_t)b * SPRQ + i) * 3;
  const float p0 = tr[0] + sinf(pos);
  const float p1 = tr[1] + sinf(pos * PEF1);
  const float p2 = tr[2] + sinf(pos * PEF2);

  // self-attn qkv
  const float q0 = a1w[0] * p0 + a1w[1] * p1 + a1w[2] * p2 + a1b[0];
  const float q1 = a1w[3] * p0 + a1w[4] * p1 + a1w[5] * p2 + a1b[1];
  const float q2 = a1w[6] * p0 + a1w[7] * p1 + a1w[8] * p2 + a1b[2];
  const float k0 = a1w[9]  * p0 + a1w[10] * p1 + a1w[11] * p2 + a1b[3];
  const float k1 = a1w[12] * p0 + a1w[13] * p1 + a1w[14] * p2 + a1b[4];
  const float k2 = a1w[15] * p0 + a1w[16] * p1 + a1w[17] * p2 + a1b[5];
  const float v0 = a1w[18] * p0 + a1w[19] * p1 + a1w[20] * p2 + a1b[6];
  const float v1 = a1w[21] * p0 + a1w[22] * p1 + a1w[23] * p2 + a1b[7];
  const float v2 = a1w[24] * p0 + a1w[25] * p1 + a1w[26] * p2 + a1b[8];
  sKs[i] = make_float4(k0, k1, k2, 0.f);
  sVs[i] = make_float4(v0, v1, v2, 0.f);
  __syncthreads();

  // self-attn: reference ADDS tril(ones) to scores (not -inf masking!)
  float den = 0.f, o0 = 0.f, o1 = 0.f, o2 = 0.f;
  for (int j = 0; j < SPRQ; ++j) {
    const float4 kk = sKs[j];
    const float4 vv = sVs[j];
    float s = (q0 * kk.x + q1 * kk.y + q2 * kk.z) * ISQ3 + ((j <= i) ? 1.f : 0.f);
    const float e = __expf(s);
    den += e;
    o0 = fmaf(e, vv.x, o0); o1 = fmaf(e, vv.y, o1); o2 = fmaf(e, vv.z, o2);
  }
  float rd = 1.f / den;
  o0 *= rd; o1 *= rd; o2 *= rd;

  float r0 = a1ow[0] * o0 + a1ow[1] * o1 + a1ow[2] * o2 + a1ob[0] + p0;
  float r1 = a1ow[3] * o0 + a1ow[4] * o1 + a1ow[5] * o2 + a1ob[1] + p1;
  float r2 = a1ow[6] * o0 + a1ow[7] * o1 + a1ow[8] * o2 + a1ob[2] + p2;

  float mean, rstd;
  block_stats(r0 + r1 + r2, r0 * r0 + r1 * r1 + r2 * r2, sRed, i, 128, 384.f, mean, rstd);
  const int li = i * 3;
  const float x20 = (r0 - mean) * rstd * ln1w[li + 0] + ln1b[li + 0];
  const float x21 = (r1 - mean) * rstd * ln1w[li + 1] + ln1b[li + 1];
  const float x22 = (r2 - mean) * rstd * ln1w[li + 2] + ln1b[li + 2];

  // cross-attn (q from x2; K,V staged from enc_out)
  const float cq0 = a2w[0] * x20 + a2w[1] * x21 + a2w[2] * x22 + a2b[0];
  const float cq1 = a2w[3] * x20 + a2w[4] * x21 + a2w[5] * x22 + a2b[1];
  const float cq2 = a2w[6] * x20 + a2w[7] * x21 + a2w[8] * x22 + a2b[2];
  den = 0.f; o0 = 0.f; o1 = 0.f; o2 = 0.f;
  for (int j = 0; j < SINQ; ++j) {
    const float4 kk = sKc[j];
    const float4 vv = sVc[j];
    const float e = __expf((cq0 * kk.x + cq1 * kk.y + cq2 * kk.z) * ISQ3);
    den += e;
    o0 = fmaf(e, vv.x, o0); o1 = fmaf(e, vv.y, o1); o2 = fmaf(e, vv.z, o2);
  }
  rd = 1.f / den;
  o0 *= rd; o1 *= rd; o2 *= rd;

  r0 = a2ow[0] * o0 + a2ow[1] * o1 + a2ow[2] * o2 + a2ob[0] + x20;
  r1 = a2ow[3] * o0 + a2ow[4] * o1 + a2ow[5] * o2 + a2ob[1] + x21;
  r2 = a2ow[6] * o0 + a2ow[7] * o1 + a2ow[8] * o2 + a2ob[2] + x22;

  // x3 = LN(a + x2) with dec_ln1 weights AGAIN (per reference)
  block_stats(r0 + r1 + r2, r0 * r0 + r1 * r1 + r2 * r2, sRed, i, 128, 384.f, mean, rstd);
  const float x30 = (r0 - mean) * rstd * ln1w[li + 0] + ln1b[li + 0];
  const float x31 = (r1 - mean) * rstd * ln1w[li + 1] + ln1b[li + 1];
  const float x32 = (r2 - mean) * rstd * ln1w[li + 2] + ln1b[li + 2];

  // FFN
  float c0 = 0.f, c1 = 0.f, c2 = 0.f;
  for (int k = 0; k < HIDQ; ++k) {
    const float4 wr = sW1[k];
    float h = fmaf(wr.x, x30, fmaf(wr.y, x31, fmaf(wr.z, x32, wr.w)));
    h = fmaxf(h, 0.f);
    const float4 wc = sW2[k];
    c0 = fmaf(h, wc.x, c0); c1 = fmaf(h, wc.y, c1); c2 = fmaf(h, wc.z, c2);
  }
  const float h0 = c0 + b2[0] + x30;
  const float h1 = c1 + b2[1] + x31;
  const float h2 = c2 + b2[2] + x32;

  block_stats(h0 + h1 + h2, h0 * h0 + h1 * h1 + h2 * h2, sRed, i, 128, 384.f, mean, rstd);
  float* op = out + ((size_t)b * SPRQ + i) * 3;
  op[0] = (h0 - mean) * rstd * ln3w[li + 0] + ln3b[li + 0];
  op[1] = (h1 - mean) * rstd * ln3w[li + 1] + ln3b[li + 1];
  op[2] = (h2 - mean) * rstd * ln3w[li + 2] + ln3b[li + 2];
}

extern "C" void kernel_launch(void* const* d_in, const int* in_sizes, int n_in,
                              void* d_out, int out_size, void* d_ws, size_t ws_size,
                              hipStream_t stream) {
  (void)in_sizes; (void)n_in; (void)out_size; (void)ws_size;
  const float* X = (const float*)d_in[0];
  const float* T = (const float*)d_in[1];
  float* enc_ws = (float*)d_ws;  // 1024*256*3 f32 = 3 MB

  enc_fwd<<<NB, 256, 0, stream>>>(
      X,
      (const float*)d_in[2],  (const float*)d_in[3],
      (const float*)d_in[4],  (const float*)d_in[5],
      (const float*)d_in[6],  (const float*)d_in[7],
      (const float*)d_in[8],  (const float*)d_in[9],
      (const float*)d_in[10], (const float*)d_in[11],
      (const float*)d_in[12], (const float*)d_in[13],
      enc_ws);

  dec_fwd<<<NB, 128, 0, stream>>>(
      T, enc_ws,
      (const float*)d_in[14], (const float*)d_in[15],
      (const float*)d_in[16], (const float*)d_in[17],
      (const float*)d_in[18], (const float*)d_in[19],
      (const float*)d_in[20], (const float*)d_in[21],
      (const float*)d_in[22], (const float*)d_in[23],
      (const float*)d_in[24], (const float*)d_in[25],
      (const float*)d_in[26], (const float*)d_in[27],
      (const float*)d_in[28], (const float*)d_in[29],
      (float*)d_out);
}